// Round 19
// baseline (348.381 us; speedup 1.0000x reference)
//
#include <hip/hip_runtime.h>
#include <hip/hip_bf16.h>

// NodeNetwork: mi = segsum(ea*x[row] -> col), mo = segsum(ea*x[col] -> row)
// out = tanh(tanh([mi|mo|x] @ W1 + b1) @ W2 + b2)
// N=100000, D=32, O=64, E=1600000
//
// R19: MLP operand-pipe split. R18 (W in VGPR + uniform s_load M) only -7us:
// 110 VGPR capped occupancy at 4 waves/SIMD, s_load latency exposed. Now:
// W in LDS (conflict-free: lane o reads w[k*64+o]), M row via uniform
// s_load (SGPR operand), fma = 1 SGPR + 1 LDS-VGPR + acc (legal mix),
// VGPR ~40 -> 8 waves/SIMD; 512-thr blocks, wave=node, 1024-block
// grid-stride so W staged only 1024x. l1 LDS-pipe floor ~16us, l2 ~10us.
// accum/partition/hist = R15 (accum 96us @ 47% occ).

#define DFEAT 32
#define OFEAT 64
#define EPB   2048            // edges per partition block -> 4096 records
#define KEYS_PER_BIN 128      // partition bin = key >> 7 ; lkey = key & 127
#define NBINMAX 1568
#define CAP   3072            // records staged per chunk (24 KB)

typedef unsigned long long u64;

__device__ __forceinline__ float rdlane(float v, int l) {
    return __int_as_float(__builtin_amdgcn_readlane(__float_as_int(v), l));
}

// ---- A. per-block histogram over bins (512 thr, int4 loads) ----
__global__ __launch_bounds__(512) void hist_part(
    const int* __restrict__ ei, int* __restrict__ blockhist, int E, int NBIN)
{
    __shared__ int lh[NBINMAX];
    int blk = blockIdx.x, tid = threadIdx.x;
    for (int i = tid; i < NBIN; i += 512) lh[i] = 0;
    __syncthreads();
    int e0 = blk * EPB;
    if (e0 + EPB <= E) {
        int4 rr = *(const int4*)(ei + e0 + tid * 4);
        int4 cc = *(const int4*)(ei + E + e0 + tid * 4);
        atomicAdd(&lh[(2 * cc.x) >> 7], 1); atomicAdd(&lh[(2 * rr.x + 1) >> 7], 1);
        atomicAdd(&lh[(2 * cc.y) >> 7], 1); atomicAdd(&lh[(2 * rr.y + 1) >> 7], 1);
        atomicAdd(&lh[(2 * cc.z) >> 7], 1); atomicAdd(&lh[(2 * rr.z + 1) >> 7], 1);
        atomicAdd(&lh[(2 * cc.w) >> 7], 1); atomicAdd(&lh[(2 * rr.w + 1) >> 7], 1);
    } else {
        #pragma unroll
        for (int j = 0; j < 4; ++j) {
            int e = e0 + tid * 4 + j;
            if (e < E) {
                atomicAdd(&lh[(2 * ei[E + e]) >> 7], 1);
                atomicAdd(&lh[(2 * ei[e] + 1) >> 7], 1);
            }
        }
    }
    __syncthreads();
    for (int i = tid; i < NBIN; i += 512)
        blockhist[(long long)blk * NBIN + i] = lh[i];
}

// ---- B. column scan: per-bin prefix over blocks -> ofsT, bintotal ----
__global__ __launch_bounds__(64) void colscan(
    const int* __restrict__ blockhist, int* __restrict__ ofsT,
    int* __restrict__ bintotal, int nPB, int NBIN)
{
    int bin  = blockIdx.x;
    int lane = threadIdx.x;
    int run = 0;
    for (int b0 = 0; b0 < nPB; b0 += 64) {
        int b = b0 + lane;
        int v = (b < nPB) ? blockhist[(long long)b * NBIN + bin] : 0;
        int s = v;
        #pragma unroll
        for (int d = 1; d < 64; d <<= 1) {
            int t = __shfl_up(s, d, 64);
            if (lane >= d) s += t;
        }
        if (b < nPB) ofsT[(long long)bin * nPB + b] = s - v + run;
        run += __shfl(s, 63, 64);
    }
    if (lane == 0) bintotal[bin] = run;
}

// ---- C. exclusive scan of (even-padded) bin totals ----
__global__ __launch_bounds__(1024) void scan_bins(
    const int* __restrict__ bintotal, int* __restrict__ binbase, int NBIN)
{
    __shared__ int s[1024];
    int t = threadIdx.x;
    int i0 = 2 * t, i1 = 2 * t + 1;
    int p0 = (i0 < NBIN) ? ((bintotal[i0] + 1) & ~1) : 0;
    int p1 = (i1 < NBIN) ? ((bintotal[i1] + 1) & ~1) : 0;
    int v = p0 + p1;
    s[t] = v;
    __syncthreads();
    for (int o = 1; o < 1024; o <<= 1) {
        int u = (t >= o) ? s[t - o] : 0;
        __syncthreads();
        s[t] += u;
        __syncthreads();
    }
    int excl = s[t] - v;
    if (i0 < NBIN) binbase[i0] = excl;
    if (i1 < NBIN) binbase[i1] = excl + p0;
}

// ---- D. partition: 512 thr, int4 loads, 48KB LDS, binary-search flush ----
__global__ __launch_bounds__(512) void partition_kernel(
    const int* __restrict__ ei, const float* __restrict__ ea,
    const int* __restrict__ ofsT, const int* __restrict__ binbase,
    u64* __restrict__ pay, int E, int NBIN, int nPB)
{
    __shared__ unsigned short lofsw[NBINMAX + 1];
    __shared__ int lcur[NBINMAX];
    __shared__ int lbase[NBINMAX];
    __shared__ u64 stag[2 * EPB];                  // 32 KB
    int blk = blockIdx.x, tid = threadIdx.x;
    int e0 = blk * EPB;

    for (int i = tid; i < NBIN; i += 512) lcur[i] = 0;
    __syncthreads();

    int4 rr, cc; float4 av; bool full = (e0 + EPB <= E);
    if (full) {
        rr = *(const int4*)(ei + e0 + tid * 4);
        cc = *(const int4*)(ei + E + e0 + tid * 4);
        av = *(const float4*)(ea + e0 + tid * 4);
        atomicAdd(&lcur[(2 * cc.x) >> 7], 1); atomicAdd(&lcur[(2 * rr.x + 1) >> 7], 1);
        atomicAdd(&lcur[(2 * cc.y) >> 7], 1); atomicAdd(&lcur[(2 * rr.y + 1) >> 7], 1);
        atomicAdd(&lcur[(2 * cc.z) >> 7], 1); atomicAdd(&lcur[(2 * rr.z + 1) >> 7], 1);
        atomicAdd(&lcur[(2 * cc.w) >> 7], 1); atomicAdd(&lcur[(2 * rr.w + 1) >> 7], 1);
    } else {
        int rs[4], cs[4]; float as[4];
        #pragma unroll
        for (int j = 0; j < 4; ++j) {
            int e = e0 + tid * 4 + j;
            if (e < E) {
                rs[j] = ei[e]; cs[j] = ei[E + e]; as[j] = ea[e];
                atomicAdd(&lcur[(2 * cs[j]) >> 7], 1);
                atomicAdd(&lcur[(2 * rs[j] + 1) >> 7], 1);
            } else { rs[j] = 0; cs[j] = 0; as[j] = 0.0f; }
        }
        rr = make_int4(rs[0], rs[1], rs[2], rs[3]);
        cc = make_int4(cs[0], cs[1], cs[2], cs[3]);
        av = make_float4(as[0], as[1], as[2], as[3]);
    }
    __syncthreads();

    if (tid < 64) {
        int runc = 0;
        for (int b0 = 0; b0 < NBIN; b0 += 64) {
            int i = b0 + tid;
            int v = (i < NBIN) ? lcur[i] : 0;
            int s = v;
            #pragma unroll
            for (int d = 1; d < 64; d <<= 1) {
                int t2 = __shfl_up(s, d, 64);
                if (tid >= d) s += t2;
            }
            if (i < NBIN) lofsw[i] = (unsigned short)(s - v + runc);
            runc += __shfl(s, 63, 64);
        }
        if (tid == 0) lofsw[NBIN] = (unsigned short)runc;
    }
    __syncthreads();

    for (int i = tid; i < NBIN; i += 512) {
        lcur[i] = 0;
        lbase[i] = binbase[i] + ofsT[(long long)i * nPB + blk];
    }
    __syncthreads();

    {
        int rs[4] = {rr.x, rr.y, rr.z, rr.w};
        int cs[4] = {cc.x, cc.y, cc.z, cc.w};
        float as[4] = {av.x, av.y, av.z, av.w};
        #pragma unroll
        for (int j = 0; j < 4; ++j) {
            int e = e0 + tid * 4 + j;
            if (e < E) {
                unsigned int ab = (unsigned int)__float_as_int(as[j]);
                {
                    int key = 2 * cs[j]; int bin = key >> 7;      // mi: src = r
                    int t2 = atomicAdd(&lcur[bin], 1);
                    stag[(int)lofsw[bin] + t2] = ((u64)ab << 32) |
                        (unsigned int)(rs[j] | ((key & 127) << 17));
                }
                {
                    int key = 2 * rs[j] + 1; int bin = key >> 7;  // mo: src = c
                    int t2 = atomicAdd(&lcur[bin], 1);
                    stag[(int)lofsw[bin] + t2] = ((u64)ab << 32) |
                        (unsigned int)(cs[j] | ((key & 127) << 17));
                }
            }
        }
    }
    __syncthreads();

    int total = lofsw[NBIN];
    for (int i = tid; i < total; i += 512) {
        int lo = 0, hi = NBIN;
        while (hi - lo > 1) {
            int mid = (lo + hi) >> 1;
            if ((int)lofsw[mid] <= i) lo = mid; else hi = mid;
        }
        pay[lbase[lo] + (i - (int)lofsw[lo])] = stag[i];
    }
}

// ---- E. accum: 512 thr / 8 waves; ONE bin per block (R13/R15 config) ----
__global__ __launch_bounds__(512) void accum_sortgather(
    const float* __restrict__ x,
    const int* __restrict__ binbase, const int* __restrict__ bintotal,
    const u64* __restrict__ pay,
    float* __restrict__ mi, float* __restrict__ mo, int NK)
{
    __shared__ u64 srec[CAP];
    __shared__ int lcnt[KEYS_PER_BIN];
    __shared__ int lofs[KEYS_PER_BIN];
    __shared__ int lcur[KEYS_PER_BIN];

    int b = blockIdx.x, tid = threadIdx.x;
    int base = binbase[b];
    int n    = bintotal[b];
    int wid  = tid >> 6;
    int lane = tid & 63;
    int half = lane >> 5;
    int feat = lane & 31;

    float accA[4], accB[4], accC[4], accD[4];
    #pragma unroll
    for (int p = 0; p < 4; ++p) {
        accA[p] = 0.0f; accB[p] = 0.0f; accC[p] = 0.0f; accD[p] = 0.0f;
    }

    for (int c0 = 0; c0 < n; c0 += CAP) {
        int cn = min(n - c0, CAP);
        if (tid < KEYS_PER_BIN) lcnt[tid] = 0;
        __syncthreads();
        for (int i = tid; i < cn; i += 512)
            atomicAdd(&lcnt[((int)pay[base + c0 + i] >> 17) & 127], 1);
        __syncthreads();
        if (tid < 64) {
            int v0 = lcnt[2 * tid], v1 = lcnt[2 * tid + 1];
            int s = v0 + v1, ss = s;
            #pragma unroll
            for (int d = 1; d < 64; d <<= 1) {
                int t = __shfl_up(ss, d, 64);
                if (tid >= d) ss += t;
            }
            int excl = ss - s;
            lofs[2 * tid] = excl;      lofs[2 * tid + 1] = excl + v0;
            lcur[2 * tid] = excl;      lcur[2 * tid + 1] = excl + v0;
        }
        __syncthreads();
        for (int i = tid; i < cn; i += 512) {
            u64 v = pay[base + c0 + i];
            int t2 = atomicAdd(&lcur[((int)v >> 17) & 127], 1);
            srec[t2] = v;
        }
        __syncthreads();

        #pragma unroll
        for (int p = 0; p < 4; ++p) {
            int kb = wid * 16 + 4 * p;
            int s0 = lofs[kb + 0], e0 = s0 + lcnt[kb + 0];
            int s1 = lofs[kb + 1], e1 = s1 + lcnt[kb + 1];
            int s2 = lofs[kb + 2], e2 = s2 + lcnt[kb + 2];
            int s3 = lofs[kb + 3], e3 = s3 + lcnt[kb + 3];
            int i0 = s0 + half, i1 = s1 + half, i2 = s2 + half, i3 = s3 + half;
            float a0 = accA[p], a1 = accB[p], a2 = accC[p], a3 = accD[p];
            while (i0 < e0 && i1 < e1 && i2 < e2 && i3 < e3) {
                u64 r0 = srec[i0], r1 = srec[i1], r2 = srec[i2], r3 = srec[i3];
                float x0 = x[(long long)((int)r0 & 0x1FFFF) * DFEAT + feat];
                float x1 = x[(long long)((int)r1 & 0x1FFFF) * DFEAT + feat];
                float x2 = x[(long long)((int)r2 & 0x1FFFF) * DFEAT + feat];
                float x3 = x[(long long)((int)r3 & 0x1FFFF) * DFEAT + feat];
                a0 = fmaf(__int_as_float((int)(r0 >> 32)), x0, a0);
                a1 = fmaf(__int_as_float((int)(r1 >> 32)), x1, a1);
                a2 = fmaf(__int_as_float((int)(r2 >> 32)), x2, a2);
                a3 = fmaf(__int_as_float((int)(r3 >> 32)), x3, a3);
                i0 += 2; i1 += 2; i2 += 2; i3 += 2;
            }
            while (i0 < e0) {
                u64 rr = srec[i0];
                a0 = fmaf(__int_as_float((int)(rr >> 32)),
                          x[(long long)((int)rr & 0x1FFFF) * DFEAT + feat], a0);
                i0 += 2;
            }
            while (i1 < e1) {
                u64 rr = srec[i1];
                a1 = fmaf(__int_as_float((int)(rr >> 32)),
                          x[(long long)((int)rr & 0x1FFFF) * DFEAT + feat], a1);
                i1 += 2;
            }
            while (i2 < e2) {
                u64 rr = srec[i2];
                a2 = fmaf(__int_as_float((int)(rr >> 32)),
                          x[(long long)((int)rr & 0x1FFFF) * DFEAT + feat], a2);
                i2 += 2;
            }
            while (i3 < e3) {
                u64 rr = srec[i3];
                a3 = fmaf(__int_as_float((int)(rr >> 32)),
                          x[(long long)((int)rr & 0x1FFFF) * DFEAT + feat], a3);
                i3 += 2;
            }
            accA[p] = a0; accB[p] = a1; accC[p] = a2; accD[p] = a3;
        }
        __syncthreads();
    }

    int key0 = b * KEYS_PER_BIN + wid * 16;
    #pragma unroll
    for (int p = 0; p < 4; ++p) {
        float t0 = accA[p] + __shfl_xor(accA[p], 32, 64);
        float t1 = accB[p] + __shfl_xor(accB[p], 32, 64);
        float t2 = accC[p] + __shfl_xor(accC[p], 32, 64);
        float t3 = accD[p] + __shfl_xor(accD[p], 32, 64);
        float vA = half ? t2 : t0;
        float vB = half ? t3 : t1;
        int gkA = key0 + 4 * p + (half ? 2 : 0);
        int gkB = gkA + 1;
        if (gkA < NK) {
            int node = gkA >> 1;
            ((gkA & 1) ? mo : mi)[(long long)node * DFEAT + feat] = vA;
        }
        if (gkB < NK) {
            int node = gkB >> 1;
            ((gkB & 1) ? mo : mi)[(long long)node * DFEAT + feat] = vB;
        }
    }
}

// ---- F1. MLP layer 1: W1 in LDS, M row via uniform s_load; wave = node ----
__global__ __launch_bounds__(512) void mlp_l1(
    const float* __restrict__ mi, const float* __restrict__ mo,
    const float* __restrict__ x,
    const float* __restrict__ W1, const float* __restrict__ b1,
    float* __restrict__ hbuf, int N)
{
    __shared__ float sW1[96 * 64];     // 24 KB
    int o  = threadIdx.x & 63;
    int wv = threadIdx.x >> 6;         // 0..7

    for (int i = threadIdx.x; i < 96 * 64; i += 512) sW1[i] = W1[i];
    __syncthreads();
    float bias1 = b1[o];

    int stride = gridDim.x * 8;
    for (int node = blockIdx.x * 8 + wv; node < N; node += stride) {
        const float* Mi = mi + (long long)node * DFEAT;   // uniform
        const float* Mo = mo + (long long)node * DFEAT;
        const float* Xr = x  + (long long)node * DFEAT;

        float a0 = bias1, a1 = 0.0f, a2 = 0.0f, a3 = 0.0f;
        #pragma unroll
        for (int k = 0; k < 32; k += 4) {
            a0 = fmaf(Mi[k + 0], sW1[(k + 0) * 64 + o], a0);
            a1 = fmaf(Mi[k + 1], sW1[(k + 1) * 64 + o], a1);
            a2 = fmaf(Mi[k + 2], sW1[(k + 2) * 64 + o], a2);
            a3 = fmaf(Mi[k + 3], sW1[(k + 3) * 64 + o], a3);
        }
        #pragma unroll
        for (int k = 0; k < 32; k += 4) {
            a0 = fmaf(Mo[k + 0], sW1[(32 + k + 0) * 64 + o], a0);
            a1 = fmaf(Mo[k + 1], sW1[(32 + k + 1) * 64 + o], a1);
            a2 = fmaf(Mo[k + 2], sW1[(32 + k + 2) * 64 + o], a2);
            a3 = fmaf(Mo[k + 3], sW1[(32 + k + 3) * 64 + o], a3);
        }
        #pragma unroll
        for (int k = 0; k < 32; k += 4) {
            a0 = fmaf(Xr[k + 0], sW1[(64 + k + 0) * 64 + o], a0);
            a1 = fmaf(Xr[k + 1], sW1[(64 + k + 1) * 64 + o], a1);
            a2 = fmaf(Xr[k + 2], sW1[(64 + k + 2) * 64 + o], a2);
            a3 = fmaf(Xr[k + 3], sW1[(64 + k + 3) * 64 + o], a3);
        }
        hbuf[(long long)node * OFEAT + o] = tanhf(((a0 + a1) + (a2 + a3)));
    }
}

// ---- F2. MLP layer 2: W2 in LDS, h row via uniform s_load; wave = node ----
__global__ __launch_bounds__(512) void mlp_l2(
    const float* __restrict__ hbuf,
    const float* __restrict__ W2, const float* __restrict__ b2,
    float* __restrict__ out, int N)
{
    __shared__ float sW2[64 * 64];     // 16 KB
    int o  = threadIdx.x & 63;
    int wv = threadIdx.x >> 6;

    for (int i = threadIdx.x; i < 64 * 64; i += 512) sW2[i] = W2[i];
    __syncthreads();
    float bias2 = b2[o];

    int stride = gridDim.x * 8;
    for (int node = blockIdx.x * 8 + wv; node < N; node += stride) {
        const float* H = hbuf + (long long)node * OFEAT;  // uniform

        float c0 = bias2, c1 = 0.0f, c2 = 0.0f, c3 = 0.0f;
        #pragma unroll
        for (int k = 0; k < 64; k += 4) {
            c0 = fmaf(H[k + 0], sW2[(k + 0) * 64 + o], c0);
            c1 = fmaf(H[k + 1], sW2[(k + 1) * 64 + o], c1);
            c2 = fmaf(H[k + 2], sW2[(k + 2) * 64 + o], c2);
            c3 = fmaf(H[k + 3], sW2[(k + 3) * 64 + o], c3);
        }
        out[(long long)node * OFEAT + o] = tanhf(((c0 + c1) + (c2 + c3)));
    }
}

// ---- fallback: direct atomic scatter (ws too small / N too big) ----
__global__ __launch_bounds__(256) void edge_scatter_kernel(
    const float* __restrict__ x, const int* __restrict__ ei,
    const float* __restrict__ ea,
    float* __restrict__ mi, float* __restrict__ mo, int E)
{
    long long tid = (long long)blockIdx.x * blockDim.x + threadIdx.x;
    long long total = (long long)E * 8;
    if (tid >= total) return;
    int e = (int)(tid >> 3);
    int q = (int)(tid & 7);
    int r = ei[e];
    int c = ei[E + e];
    float a = ea[e];
    const float4* x4 = (const float4*)x;
    float4 xr = x4[(long long)r * 8 + q];
    float4 xc = x4[(long long)c * 8 + q];
    float* mip = mi + (long long)c * DFEAT + q * 4;
    float* mop = mo + (long long)r * DFEAT + q * 4;
    atomicAdd(mip + 0, a * xr.x); atomicAdd(mip + 1, a * xr.y);
    atomicAdd(mip + 2, a * xr.z); atomicAdd(mip + 3, a * xr.w);
    atomicAdd(mop + 0, a * xc.x); atomicAdd(mop + 1, a * xc.y);
    atomicAdd(mop + 2, a * xc.z); atomicAdd(mop + 3, a * xc.w);
}

// ---- fallback MLP (R15 readlane form) ----
__global__ __launch_bounds__(256) void mlp_reg_kernel(
    const float* __restrict__ mi, const float* __restrict__ mo,
    const float* __restrict__ x,
    const float* __restrict__ W1, const float* __restrict__ b1,
    const float* __restrict__ W2, const float* __restrict__ b2,
    float* __restrict__ out, int N)
{
    int o   = threadIdx.x & 63;
    int wid = threadIdx.x >> 6;

    float w1r[96], w2r[64];
    #pragma unroll
    for (int k = 0; k < 96; ++k) w1r[k] = W1[k * 64 + o];
    #pragma unroll
    for (int k = 0; k < 64; ++k) w2r[k] = W2[k * 64 + o];
    float bias1 = b1[o];
    float bias2 = b2[o];

    int stride = gridDim.x * 4;
    for (int node = blockIdx.x * 4 + wid; node < N; node += stride) {
        long long nb = (long long)node * DFEAT;
        float m01 = (o < 32) ? mi[nb + o] : mo[nb + (o - 32)];
        float m2v = (o < 32) ? x[nb + o] : 0.0f;

        float a0 = bias1, a1 = 0.0f, a2 = 0.0f, a3 = 0.0f;
        #pragma unroll
        for (int k = 0; k < 64; k += 4) {
            a0 = fmaf(rdlane(m01, k + 0), w1r[k + 0], a0);
            a1 = fmaf(rdlane(m01, k + 1), w1r[k + 1], a1);
            a2 = fmaf(rdlane(m01, k + 2), w1r[k + 2], a2);
            a3 = fmaf(rdlane(m01, k + 3), w1r[k + 3], a3);
        }
        #pragma unroll
        for (int k = 0; k < 32; k += 4) {
            a0 = fmaf(rdlane(m2v, k + 0), w1r[64 + k + 0], a0);
            a1 = fmaf(rdlane(m2v, k + 1), w1r[64 + k + 1], a1);
            a2 = fmaf(rdlane(m2v, k + 2), w1r[64 + k + 2], a2);
            a3 = fmaf(rdlane(m2v, k + 3), w1r[64 + k + 3], a3);
        }
        float h = tanhf(((a0 + a1) + (a2 + a3)));

        float c0 = bias2, c1 = 0.0f, c2 = 0.0f, c3 = 0.0f;
        #pragma unroll
        for (int k = 0; k < 64; k += 4) {
            c0 = fmaf(rdlane(h, k + 0), w2r[k + 0], c0);
            c1 = fmaf(rdlane(h, k + 1), w2r[k + 1], c1);
            c2 = fmaf(rdlane(h, k + 2), w2r[k + 2], c2);
            c3 = fmaf(rdlane(h, k + 3), w2r[k + 3], c3);
        }
        out[(long long)node * OFEAT + o] = tanhf(((c0 + c1) + (c2 + c3)));
    }
}

extern "C" void kernel_launch(void* const* d_in, const int* in_sizes, int n_in,
                              void* d_out, int out_size, void* d_ws, size_t ws_size,
                              hipStream_t stream) {
    const float* x  = (const float*)d_in[0];
    const int*   ei = (const int*)  d_in[1];
    const float* ea = (const float*)d_in[2];
    const float* W1 = (const float*)d_in[3];
    const float* b1 = (const float*)d_in[4];
    const float* W2 = (const float*)d_in[5];
    const float* b2 = (const float*)d_in[6];
    float* out = (float*)d_out;

    int N    = in_sizes[0] / DFEAT;              // 100000
    int E    = in_sizes[2];                      // 1600000
    int NK   = 2 * N;
    int NBIN = (NK + KEYS_PER_BIN - 1) / KEYS_PER_BIN;   // 1563
    int nPB  = (E + EPB - 1) / EPB;                      // 782

    float* mi = (float*)d_ws;
    float* mo = mi + (size_t)N * DFEAT;

    size_t paySlots = (size_t)2 * E + NBIN;
    size_t need = (size_t)N * DFEAT * 2 * 4
                + paySlots * 8
                + (size_t)nPB * NBIN * 4 * 2
                + (size_t)NBIN * 4 * 2 + 64;

    bool h_fits = (size_t)N * OFEAT * 4 <= paySlots * 8;

    if (ws_size >= need && N <= (1 << 17) && NBIN <= NBINMAX && h_fits) {
        u64* pay       = (u64*)(mo + (size_t)N * DFEAT);
        int* blockhist = (int*)(pay + paySlots);
        int* ofsT      = blockhist + (size_t)nPB * NBIN;
        int* bintotal  = ofsT + (size_t)nPB * NBIN;
        int* binbase   = bintotal + NBIN;

        hist_part<<<nPB, 512, 0, stream>>>(ei, blockhist, E, NBIN);
        colscan<<<NBIN, 64, 0, stream>>>(blockhist, ofsT, bintotal, nPB, NBIN);
        scan_bins<<<1, 1024, 0, stream>>>(bintotal, binbase, NBIN);
        partition_kernel<<<nPB, 512, 0, stream>>>(ei, ea, ofsT, binbase,
                                                  pay, E, NBIN, nPB);
        accum_sortgather<<<NBIN, 512, 0, stream>>>(x, binbase, bintotal, pay,
                                                   mi, mo, NK);
        float* hbuf = (float*)pay;               // pay dead after accum
        mlp_l1<<<1024, 512, 0, stream>>>(mi, mo, x, W1, b1, hbuf, N);
        mlp_l2<<<1024, 512, 0, stream>>>(hbuf, W2, b2, out, N);
    } else {
        hipMemsetAsync(d_ws, 0, (size_t)N * DFEAT * 2 * sizeof(float), stream);
        long long total = (long long)E * 8;
        int nblocks = (int)((total + 255) / 256);
        edge_scatter_kernel<<<nblocks, 256, 0, stream>>>(x, ei, ea, mi, mo, E);
        mlp_reg_kernel<<<512, 256, 0, stream>>>(mi, mo, x, W1, b1, W2, b2, out, N);
    }
}

// Round 20
// 262.510 us; speedup vs baseline: 1.3271x; 1.3271x over previous
//
#include <hip/hip_runtime.h>
#include <hip/hip_bf16.h>

// NodeNetwork: mi = segsum(ea*x[row] -> col), mo = segsum(ea*x[col] -> row)
// out = tanh(tanh([mi|mo|x] @ W1 + b1) @ W2 + b2)
// N=100000, D=32, O=64, E=1600000
//
// R20: MLP reverted to R18's proven form (W in VGPR, 64-thr uniform-node
// blocks; R19's LDS-weight variant put 96 ds_reads on every node's critical
// path -> 127us). accum deepened to 8 INDEPENDENT key-chains per half-wave
// (2 groups of 8 distinct keys; 8 x-loads in flight vs 4) while staying
// under the 64-VGPR occupancy cliff that killed R12 (VGPR 68).
// R18 baseline: 231.6us (accum 96 @ 47% occ, 4 chains).

#define DFEAT 32
#define OFEAT 64
#define EPB   2048            // edges per partition block -> 4096 records
#define KEYS_PER_BIN 128      // partition bin = key >> 7 ; lkey = key & 127
#define NBINMAX 1568
#define CAP   3072            // records staged per chunk (24 KB)

typedef unsigned long long u64;

__device__ __forceinline__ float rdlane(float v, int l) {
    return __int_as_float(__builtin_amdgcn_readlane(__float_as_int(v), l));
}

// ---- A. per-block histogram over bins (512 thr, int4 loads) ----
__global__ __launch_bounds__(512) void hist_part(
    const int* __restrict__ ei, int* __restrict__ blockhist, int E, int NBIN)
{
    __shared__ int lh[NBINMAX];
    int blk = blockIdx.x, tid = threadIdx.x;
    for (int i = tid; i < NBIN; i += 512) lh[i] = 0;
    __syncthreads();
    int e0 = blk * EPB;
    if (e0 + EPB <= E) {
        int4 rr = *(const int4*)(ei + e0 + tid * 4);
        int4 cc = *(const int4*)(ei + E + e0 + tid * 4);
        atomicAdd(&lh[(2 * cc.x) >> 7], 1); atomicAdd(&lh[(2 * rr.x + 1) >> 7], 1);
        atomicAdd(&lh[(2 * cc.y) >> 7], 1); atomicAdd(&lh[(2 * rr.y + 1) >> 7], 1);
        atomicAdd(&lh[(2 * cc.z) >> 7], 1); atomicAdd(&lh[(2 * rr.z + 1) >> 7], 1);
        atomicAdd(&lh[(2 * cc.w) >> 7], 1); atomicAdd(&lh[(2 * rr.w + 1) >> 7], 1);
    } else {
        #pragma unroll
        for (int j = 0; j < 4; ++j) {
            int e = e0 + tid * 4 + j;
            if (e < E) {
                atomicAdd(&lh[(2 * ei[E + e]) >> 7], 1);
                atomicAdd(&lh[(2 * ei[e] + 1) >> 7], 1);
            }
        }
    }
    __syncthreads();
    for (int i = tid; i < NBIN; i += 512)
        blockhist[(long long)blk * NBIN + i] = lh[i];
}

// ---- B. column scan: per-bin prefix over blocks -> ofsT, bintotal ----
__global__ __launch_bounds__(64) void colscan(
    const int* __restrict__ blockhist, int* __restrict__ ofsT,
    int* __restrict__ bintotal, int nPB, int NBIN)
{
    int bin  = blockIdx.x;
    int lane = threadIdx.x;
    int run = 0;
    for (int b0 = 0; b0 < nPB; b0 += 64) {
        int b = b0 + lane;
        int v = (b < nPB) ? blockhist[(long long)b * NBIN + bin] : 0;
        int s = v;
        #pragma unroll
        for (int d = 1; d < 64; d <<= 1) {
            int t = __shfl_up(s, d, 64);
            if (lane >= d) s += t;
        }
        if (b < nPB) ofsT[(long long)bin * nPB + b] = s - v + run;
        run += __shfl(s, 63, 64);
    }
    if (lane == 0) bintotal[bin] = run;
}

// ---- C. exclusive scan of (even-padded) bin totals ----
__global__ __launch_bounds__(1024) void scan_bins(
    const int* __restrict__ bintotal, int* __restrict__ binbase, int NBIN)
{
    __shared__ int s[1024];
    int t = threadIdx.x;
    int i0 = 2 * t, i1 = 2 * t + 1;
    int p0 = (i0 < NBIN) ? ((bintotal[i0] + 1) & ~1) : 0;
    int p1 = (i1 < NBIN) ? ((bintotal[i1] + 1) & ~1) : 0;
    int v = p0 + p1;
    s[t] = v;
    __syncthreads();
    for (int o = 1; o < 1024; o <<= 1) {
        int u = (t >= o) ? s[t - o] : 0;
        __syncthreads();
        s[t] += u;
        __syncthreads();
    }
    int excl = s[t] - v;
    if (i0 < NBIN) binbase[i0] = excl;
    if (i1 < NBIN) binbase[i1] = excl + p0;
}

// ---- D. partition: 512 thr, int4 loads, 48KB LDS, binary-search flush ----
__global__ __launch_bounds__(512) void partition_kernel(
    const int* __restrict__ ei, const float* __restrict__ ea,
    const int* __restrict__ ofsT, const int* __restrict__ binbase,
    u64* __restrict__ pay, int E, int NBIN, int nPB)
{
    __shared__ unsigned short lofsw[NBINMAX + 1];
    __shared__ int lcur[NBINMAX];
    __shared__ int lbase[NBINMAX];
    __shared__ u64 stag[2 * EPB];                  // 32 KB
    int blk = blockIdx.x, tid = threadIdx.x;
    int e0 = blk * EPB;

    for (int i = tid; i < NBIN; i += 512) lcur[i] = 0;
    __syncthreads();

    int4 rr, cc; float4 av; bool full = (e0 + EPB <= E);
    if (full) {
        rr = *(const int4*)(ei + e0 + tid * 4);
        cc = *(const int4*)(ei + E + e0 + tid * 4);
        av = *(const float4*)(ea + e0 + tid * 4);
        atomicAdd(&lcur[(2 * cc.x) >> 7], 1); atomicAdd(&lcur[(2 * rr.x + 1) >> 7], 1);
        atomicAdd(&lcur[(2 * cc.y) >> 7], 1); atomicAdd(&lcur[(2 * rr.y + 1) >> 7], 1);
        atomicAdd(&lcur[(2 * cc.z) >> 7], 1); atomicAdd(&lcur[(2 * rr.z + 1) >> 7], 1);
        atomicAdd(&lcur[(2 * cc.w) >> 7], 1); atomicAdd(&lcur[(2 * rr.w + 1) >> 7], 1);
    } else {
        int rs[4], cs[4]; float as[4];
        #pragma unroll
        for (int j = 0; j < 4; ++j) {
            int e = e0 + tid * 4 + j;
            if (e < E) {
                rs[j] = ei[e]; cs[j] = ei[E + e]; as[j] = ea[e];
                atomicAdd(&lcur[(2 * cs[j]) >> 7], 1);
                atomicAdd(&lcur[(2 * rs[j] + 1) >> 7], 1);
            } else { rs[j] = 0; cs[j] = 0; as[j] = 0.0f; }
        }
        rr = make_int4(rs[0], rs[1], rs[2], rs[3]);
        cc = make_int4(cs[0], cs[1], cs[2], cs[3]);
        av = make_float4(as[0], as[1], as[2], as[3]);
    }
    __syncthreads();

    if (tid < 64) {
        int runc = 0;
        for (int b0 = 0; b0 < NBIN; b0 += 64) {
            int i = b0 + tid;
            int v = (i < NBIN) ? lcur[i] : 0;
            int s = v;
            #pragma unroll
            for (int d = 1; d < 64; d <<= 1) {
                int t2 = __shfl_up(s, d, 64);
                if (tid >= d) s += t2;
            }
            if (i < NBIN) lofsw[i] = (unsigned short)(s - v + runc);
            runc += __shfl(s, 63, 64);
        }
        if (tid == 0) lofsw[NBIN] = (unsigned short)runc;
    }
    __syncthreads();

    for (int i = tid; i < NBIN; i += 512) {
        lcur[i] = 0;
        lbase[i] = binbase[i] + ofsT[(long long)i * nPB + blk];
    }
    __syncthreads();

    {
        int rs[4] = {rr.x, rr.y, rr.z, rr.w};
        int cs[4] = {cc.x, cc.y, cc.z, cc.w};
        float as[4] = {av.x, av.y, av.z, av.w};
        #pragma unroll
        for (int j = 0; j < 4; ++j) {
            int e = e0 + tid * 4 + j;
            if (e < E) {
                unsigned int ab = (unsigned int)__float_as_int(as[j]);
                {
                    int key = 2 * cs[j]; int bin = key >> 7;      // mi: src = r
                    int t2 = atomicAdd(&lcur[bin], 1);
                    stag[(int)lofsw[bin] + t2] = ((u64)ab << 32) |
                        (unsigned int)(rs[j] | ((key & 127) << 17));
                }
                {
                    int key = 2 * rs[j] + 1; int bin = key >> 7;  // mo: src = c
                    int t2 = atomicAdd(&lcur[bin], 1);
                    stag[(int)lofsw[bin] + t2] = ((u64)ab << 32) |
                        (unsigned int)(cs[j] | ((key & 127) << 17));
                }
            }
        }
    }
    __syncthreads();

    int total = lofsw[NBIN];
    for (int i = tid; i < total; i += 512) {
        int lo = 0, hi = NBIN;
        while (hi - lo > 1) {
            int mid = (lo + hi) >> 1;
            if ((int)lofsw[mid] <= i) lo = mid; else hi = mid;
        }
        pay[lbase[lo] + (i - (int)lofsw[lo])] = stag[i];
    }
}

// ---- E. accum: 512 thr / 8 waves; 8 independent key-chains per half ----
__global__ __launch_bounds__(512) void accum_sortgather(
    const float* __restrict__ x,
    const int* __restrict__ binbase, const int* __restrict__ bintotal,
    const u64* __restrict__ pay,
    float* __restrict__ mi, float* __restrict__ mo, int NK)
{
    __shared__ u64 srec[CAP];
    __shared__ int lcnt[KEYS_PER_BIN];
    __shared__ int lofs[KEYS_PER_BIN];
    __shared__ int lcur[KEYS_PER_BIN];

    int b = blockIdx.x, tid = threadIdx.x;
    int base = binbase[b];
    int n    = bintotal[b];
    int wid  = tid >> 6;        // wave owns keys [wid*16, wid*16+16)
    int lane = tid & 63;
    int half = lane >> 5;
    int feat = lane & 31;

    float acc0[8], acc1[8];     // group p=0 keys 0..7, p=1 keys 8..15
    #pragma unroll
    for (int j = 0; j < 8; ++j) { acc0[j] = 0.0f; acc1[j] = 0.0f; }

    for (int c0 = 0; c0 < n; c0 += CAP) {
        int cn = min(n - c0, CAP);
        if (tid < KEYS_PER_BIN) lcnt[tid] = 0;
        __syncthreads();
        for (int i = tid; i < cn; i += 512)
            atomicAdd(&lcnt[((int)pay[base + c0 + i] >> 17) & 127], 1);
        __syncthreads();
        if (tid < 64) {
            int v0 = lcnt[2 * tid], v1 = lcnt[2 * tid + 1];
            int s = v0 + v1, ss = s;
            #pragma unroll
            for (int d = 1; d < 64; d <<= 1) {
                int t = __shfl_up(ss, d, 64);
                if (tid >= d) ss += t;
            }
            int excl = ss - s;
            lofs[2 * tid] = excl;      lofs[2 * tid + 1] = excl + v0;
            lcur[2 * tid] = excl;      lcur[2 * tid + 1] = excl + v0;
        }
        __syncthreads();
        for (int i = tid; i < cn; i += 512) {
            u64 v = pay[base + c0 + i];
            int t2 = atomicAdd(&lcur[((int)v >> 17) & 127], 1);
            srec[t2] = v;
        }
        __syncthreads();

        // 2 groups of 8 distinct keys; 8 independent chains per half-wave
        #pragma unroll
        for (int p = 0; p < 2; ++p) {
            int kb = wid * 16 + p * 8;
            int it[8], en[8];
            #pragma unroll
            for (int j = 0; j < 8; ++j) {
                it[j] = lofs[kb + j] + half;
                en[j] = lofs[kb + j] + lcnt[kb + j];
            }
            float* acc = p ? acc1 : acc0;
            // deep loop: all 8 chains advance together
            while (it[0] < en[0] && it[1] < en[1] && it[2] < en[2] &&
                   it[3] < en[3] && it[4] < en[4] && it[5] < en[5] &&
                   it[6] < en[6] && it[7] < en[7]) {
                u64 r0 = srec[it[0]], r1 = srec[it[1]];
                u64 r2 = srec[it[2]], r3 = srec[it[3]];
                u64 r4 = srec[it[4]], r5 = srec[it[5]];
                u64 r6 = srec[it[6]], r7 = srec[it[7]];
                float x0 = x[(long long)((int)r0 & 0x1FFFF) * DFEAT + feat];
                float x1 = x[(long long)((int)r1 & 0x1FFFF) * DFEAT + feat];
                float x2 = x[(long long)((int)r2 & 0x1FFFF) * DFEAT + feat];
                float x3 = x[(long long)((int)r3 & 0x1FFFF) * DFEAT + feat];
                float x4 = x[(long long)((int)r4 & 0x1FFFF) * DFEAT + feat];
                float x5 = x[(long long)((int)r5 & 0x1FFFF) * DFEAT + feat];
                float x6 = x[(long long)((int)r6 & 0x1FFFF) * DFEAT + feat];
                float x7 = x[(long long)((int)r7 & 0x1FFFF) * DFEAT + feat];
                acc[0] = fmaf(__int_as_float((int)(r0 >> 32)), x0, acc[0]);
                acc[1] = fmaf(__int_as_float((int)(r1 >> 32)), x1, acc[1]);
                acc[2] = fmaf(__int_as_float((int)(r2 >> 32)), x2, acc[2]);
                acc[3] = fmaf(__int_as_float((int)(r3 >> 32)), x3, acc[3]);
                acc[4] = fmaf(__int_as_float((int)(r4 >> 32)), x4, acc[4]);
                acc[5] = fmaf(__int_as_float((int)(r5 >> 32)), x5, acc[5]);
                acc[6] = fmaf(__int_as_float((int)(r6 >> 32)), x6, acc[6]);
                acc[7] = fmaf(__int_as_float((int)(r7 >> 32)), x7, acc[7]);
                #pragma unroll
                for (int j = 0; j < 8; ++j) it[j] += 2;
            }
            // drain each chain
            #pragma unroll
            for (int j = 0; j < 8; ++j) {
                while (it[j] < en[j]) {
                    u64 rr = srec[it[j]];
                    acc[j] = fmaf(__int_as_float((int)(rr >> 32)),
                                  x[(long long)((int)rr & 0x1FFFF) * DFEAT + feat],
                                  acc[j]);
                    it[j] += 2;
                }
            }
        }
        __syncthreads();
    }

    // combine halves; half h writes its group's 8 keys (all lanes have t)
    int key0 = b * KEYS_PER_BIN + wid * 16;
    #pragma unroll
    for (int j = 0; j < 8; ++j) {
        float t0 = acc0[j] + __shfl_xor(acc0[j], 32, 64);
        float t1 = acc1[j] + __shfl_xor(acc1[j], 32, 64);
        float v = half ? t1 : t0;
        int gk = key0 + (half ? 8 : 0) + j;
        if (gk < NK) {
            int node = gk >> 1;
            ((gk & 1) ? mo : mi)[(long long)node * DFEAT + feat] = v;
        }
    }
}

// ---- F1. MLP layer 1 (R18 form): W1 in VGPR, 64-thr uniform-node blocks ----
__global__ __launch_bounds__(64, 4) void mlp_l1(
    const float* __restrict__ mi, const float* __restrict__ mo,
    const float* __restrict__ x,
    const float* __restrict__ W1, const float* __restrict__ b1,
    float* __restrict__ hbuf, int N)
{
    int o = threadIdx.x;

    float w1r[96];
    #pragma unroll
    for (int k = 0; k < 96; ++k) w1r[k] = W1[k * 64 + o];
    float bias1 = b1[o];

    for (int node = blockIdx.x; node < N; node += gridDim.x) {
        const float* Mi = mi + (long long)node * DFEAT;
        const float* Mo = mo + (long long)node * DFEAT;
        const float* Xr = x  + (long long)node * DFEAT;

        float a0 = bias1, a1 = 0.0f, a2 = 0.0f, a3 = 0.0f;
        #pragma unroll
        for (int k = 0; k < 32; k += 4) {
            a0 = fmaf(Mi[k + 0], w1r[k + 0], a0);
            a1 = fmaf(Mi[k + 1], w1r[k + 1], a1);
            a2 = fmaf(Mi[k + 2], w1r[k + 2], a2);
            a3 = fmaf(Mi[k + 3], w1r[k + 3], a3);
        }
        #pragma unroll
        for (int k = 0; k < 32; k += 4) {
            a0 = fmaf(Mo[k + 0], w1r[32 + k + 0], a0);
            a1 = fmaf(Mo[k + 1], w1r[32 + k + 1], a1);
            a2 = fmaf(Mo[k + 2], w1r[32 + k + 2], a2);
            a3 = fmaf(Mo[k + 3], w1r[32 + k + 3], a3);
        }
        #pragma unroll
        for (int k = 0; k < 32; k += 4) {
            a0 = fmaf(Xr[k + 0], w1r[64 + k + 0], a0);
            a1 = fmaf(Xr[k + 1], w1r[64 + k + 1], a1);
            a2 = fmaf(Xr[k + 2], w1r[64 + k + 2], a2);
            a3 = fmaf(Xr[k + 3], w1r[64 + k + 3], a3);
        }
        hbuf[(long long)node * OFEAT + o] = tanhf(((a0 + a1) + (a2 + a3)));
    }
}

// ---- F2. MLP layer 2 (R18 form) ----
__global__ __launch_bounds__(64, 5) void mlp_l2(
    const float* __restrict__ hbuf,
    const float* __restrict__ W2, const float* __restrict__ b2,
    float* __restrict__ out, int N)
{
    int o = threadIdx.x;

    float w2r[64];
    #pragma unroll
    for (int k = 0; k < 64; ++k) w2r[k] = W2[k * 64 + o];
    float bias2 = b2[o];

    for (int node = blockIdx.x; node < N; node += gridDim.x) {
        const float* H = hbuf + (long long)node * OFEAT;

        float c0 = bias2, c1 = 0.0f, c2 = 0.0f, c3 = 0.0f;
        #pragma unroll
        for (int k = 0; k < 64; k += 4) {
            c0 = fmaf(H[k + 0], w2r[k + 0], c0);
            c1 = fmaf(H[k + 1], w2r[k + 1], c1);
            c2 = fmaf(H[k + 2], w2r[k + 2], c2);
            c3 = fmaf(H[k + 3], w2r[k + 3], c3);
        }
        out[(long long)node * OFEAT + o] = tanhf(((c0 + c1) + (c2 + c3)));
    }
}

// ---- fallback: direct atomic scatter (ws too small / N too big) ----
__global__ __launch_bounds__(256) void edge_scatter_kernel(
    const float* __restrict__ x, const int* __restrict__ ei,
    const float* __restrict__ ea,
    float* __restrict__ mi, float* __restrict__ mo, int E)
{
    long long tid = (long long)blockIdx.x * blockDim.x + threadIdx.x;
    long long total = (long long)E * 8;
    if (tid >= total) return;
    int e = (int)(tid >> 3);
    int q = (int)(tid & 7);
    int r = ei[e];
    int c = ei[E + e];
    float a = ea[e];
    const float4* x4 = (const float4*)x;
    float4 xr = x4[(long long)r * 8 + q];
    float4 xc = x4[(long long)c * 8 + q];
    float* mip = mi + (long long)c * DFEAT + q * 4;
    float* mop = mo + (long long)r * DFEAT + q * 4;
    atomicAdd(mip + 0, a * xr.x); atomicAdd(mip + 1, a * xr.y);
    atomicAdd(mip + 2, a * xr.z); atomicAdd(mip + 3, a * xr.w);
    atomicAdd(mop + 0, a * xc.x); atomicAdd(mop + 1, a * xc.y);
    atomicAdd(mop + 2, a * xc.z); atomicAdd(mop + 3, a * xc.w);
}

// ---- fallback MLP (R15 readlane form) ----
__global__ __launch_bounds__(256) void mlp_reg_kernel(
    const float* __restrict__ mi, const float* __restrict__ mo,
    const float* __restrict__ x,
    const float* __restrict__ W1, const float* __restrict__ b1,
    const float* __restrict__ W2, const float* __restrict__ b2,
    float* __restrict__ out, int N)
{
    int o   = threadIdx.x & 63;
    int wid = threadIdx.x >> 6;

    float w1r[96], w2r[64];
    #pragma unroll
    for (int k = 0; k < 96; ++k) w1r[k] = W1[k * 64 + o];
    #pragma unroll
    for (int k = 0; k < 64; ++k) w2r[k] = W2[k * 64 + o];
    float bias1 = b1[o];
    float bias2 = b2[o];

    int stride = gridDim.x * 4;
    for (int node = blockIdx.x * 4 + wid; node < N; node += stride) {
        long long nb = (long long)node * DFEAT;
        float m01 = (o < 32) ? mi[nb + o] : mo[nb + (o - 32)];
        float m2v = (o < 32) ? x[nb + o] : 0.0f;

        float a0 = bias1, a1 = 0.0f, a2 = 0.0f, a3 = 0.0f;
        #pragma unroll
        for (int k = 0; k < 64; k += 4) {
            a0 = fmaf(rdlane(m01, k + 0), w1r[k + 0], a0);
            a1 = fmaf(rdlane(m01, k + 1), w1r[k + 1], a1);
            a2 = fmaf(rdlane(m01, k + 2), w1r[k + 2], a2);
            a3 = fmaf(rdlane(m01, k + 3), w1r[k + 3], a3);
        }
        #pragma unroll
        for (int k = 0; k < 32; k += 4) {
            a0 = fmaf(rdlane(m2v, k + 0), w1r[64 + k + 0], a0);
            a1 = fmaf(rdlane(m2v, k + 1), w1r[64 + k + 1], a1);
            a2 = fmaf(rdlane(m2v, k + 2), w1r[64 + k + 2], a2);
            a3 = fmaf(rdlane(m2v, k + 3), w1r[64 + k + 3], a3);
        }
        float h = tanhf(((a0 + a1) + (a2 + a3)));

        float c0 = bias2, c1 = 0.0f, c2 = 0.0f, c3 = 0.0f;
        #pragma unroll
        for (int k = 0; k < 64; k += 4) {
            c0 = fmaf(rdlane(h, k + 0), w2r[k + 0], c0);
            c1 = fmaf(rdlane(h, k + 1), w2r[k + 1], c1);
            c2 = fmaf(rdlane(h, k + 2), w2r[k + 2], c2);
            c3 = fmaf(rdlane(h, k + 3), w2r[k + 3], c3);
        }
        out[(long long)node * OFEAT + o] = tanhf(((c0 + c1) + (c2 + c3)));
    }
}

extern "C" void kernel_launch(void* const* d_in, const int* in_sizes, int n_in,
                              void* d_out, int out_size, void* d_ws, size_t ws_size,
                              hipStream_t stream) {
    const float* x  = (const float*)d_in[0];
    const int*   ei = (const int*)  d_in[1];
    const float* ea = (const float*)d_in[2];
    const float* W1 = (const float*)d_in[3];
    const float* b1 = (const float*)d_in[4];
    const float* W2 = (const float*)d_in[5];
    const float* b2 = (const float*)d_in[6];
    float* out = (float*)d_out;

    int N    = in_sizes[0] / DFEAT;              // 100000
    int E    = in_sizes[2];                      // 1600000
    int NK   = 2 * N;
    int NBIN = (NK + KEYS_PER_BIN - 1) / KEYS_PER_BIN;   // 1563
    int nPB  = (E + EPB - 1) / EPB;                      // 782

    float* mi = (float*)d_ws;
    float* mo = mi + (size_t)N * DFEAT;

    size_t paySlots = (size_t)2 * E + NBIN;
    size_t need = (size_t)N * DFEAT * 2 * 4
                + paySlots * 8
                + (size_t)nPB * NBIN * 4 * 2
                + (size_t)NBIN * 4 * 2 + 64;

    bool h_fits = (size_t)N * OFEAT * 4 <= paySlots * 8;

    if (ws_size >= need && N <= (1 << 17) && NBIN <= NBINMAX && h_fits) {
        u64* pay       = (u64*)(mo + (size_t)N * DFEAT);
        int* blockhist = (int*)(pay + paySlots);
        int* ofsT      = blockhist + (size_t)nPB * NBIN;
        int* bintotal  = ofsT + (size_t)nPB * NBIN;
        int* binbase   = bintotal + NBIN;

        hist_part<<<nPB, 512, 0, stream>>>(ei, blockhist, E, NBIN);
        colscan<<<NBIN, 64, 0, stream>>>(blockhist, ofsT, bintotal, nPB, NBIN);
        scan_bins<<<1, 1024, 0, stream>>>(bintotal, binbase, NBIN);
        partition_kernel<<<nPB, 512, 0, stream>>>(ei, ea, ofsT, binbase,
                                                  pay, E, NBIN, nPB);
        accum_sortgather<<<NBIN, 512, 0, stream>>>(x, binbase, bintotal, pay,
                                                   mi, mo, NK);
        float* hbuf = (float*)pay;               // pay dead after accum
        mlp_l1<<<4096, 64, 0, stream>>>(mi, mo, x, W1, b1, hbuf, N);
        mlp_l2<<<6144, 64, 0, stream>>>(hbuf, W2, b2, out, N);
    } else {
        hipMemsetAsync(d_ws, 0, (size_t)N * DFEAT * 2 * sizeof(float), stream);
        long long total = (long long)E * 8;
        int nblocks = (int)((total + 255) / 256);
        edge_scatter_kernel<<<nblocks, 256, 0, stream>>>(x, ei, ea, mi, mo, E);
        mlp_reg_kernel<<<512, 256, 0, stream>>>(mi, mo, x, W1, b1, W2, b2, out, N);
    }
}

// Round 21
// 231.394 us; speedup vs baseline: 1.5056x; 1.1345x over previous
//
#include <hip/hip_runtime.h>
#include <hip/hip_bf16.h>

// NodeNetwork: mi = segsum(ea*x[row] -> col), mo = segsum(ea*x[col] -> row)
// out = tanh(tanh([mi|mo|x] @ W1 + b1) @ W2 + b2)
// N=100000, D=32, O=64, E=1600000
//
// R21: revert accum to R15's quad-chain gather (R20's 8-chain joint loop
// exits at min-of-8 chain lengths -> most records in serial drain, 127us;
// quad = 96us proven). Everything else = R18/R20 best config.
// Expected ~231us: accum 96 (random-L3-bound ~4.8TB/s), MLP ~55 (VGPR-
// weight uniform-node), partition ~50, hist+scans ~25.

#define DFEAT 32
#define OFEAT 64
#define EPB   2048            // edges per partition block -> 4096 records
#define KEYS_PER_BIN 128      // partition bin = key >> 7 ; lkey = key & 127
#define NBINMAX 1568
#define CAP   3072            // records staged per chunk (24 KB)

typedef unsigned long long u64;

__device__ __forceinline__ float rdlane(float v, int l) {
    return __int_as_float(__builtin_amdgcn_readlane(__float_as_int(v), l));
}

// ---- A. per-block histogram over bins (512 thr, int4 loads) ----
__global__ __launch_bounds__(512) void hist_part(
    const int* __restrict__ ei, int* __restrict__ blockhist, int E, int NBIN)
{
    __shared__ int lh[NBINMAX];
    int blk = blockIdx.x, tid = threadIdx.x;
    for (int i = tid; i < NBIN; i += 512) lh[i] = 0;
    __syncthreads();
    int e0 = blk * EPB;
    if (e0 + EPB <= E) {
        int4 rr = *(const int4*)(ei + e0 + tid * 4);
        int4 cc = *(const int4*)(ei + E + e0 + tid * 4);
        atomicAdd(&lh[(2 * cc.x) >> 7], 1); atomicAdd(&lh[(2 * rr.x + 1) >> 7], 1);
        atomicAdd(&lh[(2 * cc.y) >> 7], 1); atomicAdd(&lh[(2 * rr.y + 1) >> 7], 1);
        atomicAdd(&lh[(2 * cc.z) >> 7], 1); atomicAdd(&lh[(2 * rr.z + 1) >> 7], 1);
        atomicAdd(&lh[(2 * cc.w) >> 7], 1); atomicAdd(&lh[(2 * rr.w + 1) >> 7], 1);
    } else {
        #pragma unroll
        for (int j = 0; j < 4; ++j) {
            int e = e0 + tid * 4 + j;
            if (e < E) {
                atomicAdd(&lh[(2 * ei[E + e]) >> 7], 1);
                atomicAdd(&lh[(2 * ei[e] + 1) >> 7], 1);
            }
        }
    }
    __syncthreads();
    for (int i = tid; i < NBIN; i += 512)
        blockhist[(long long)blk * NBIN + i] = lh[i];
}

// ---- B. column scan: per-bin prefix over blocks -> ofsT, bintotal ----
__global__ __launch_bounds__(64) void colscan(
    const int* __restrict__ blockhist, int* __restrict__ ofsT,
    int* __restrict__ bintotal, int nPB, int NBIN)
{
    int bin  = blockIdx.x;
    int lane = threadIdx.x;
    int run = 0;
    for (int b0 = 0; b0 < nPB; b0 += 64) {
        int b = b0 + lane;
        int v = (b < nPB) ? blockhist[(long long)b * NBIN + bin] : 0;
        int s = v;
        #pragma unroll
        for (int d = 1; d < 64; d <<= 1) {
            int t = __shfl_up(s, d, 64);
            if (lane >= d) s += t;
        }
        if (b < nPB) ofsT[(long long)bin * nPB + b] = s - v + run;
        run += __shfl(s, 63, 64);
    }
    if (lane == 0) bintotal[bin] = run;
}

// ---- C. exclusive scan of (even-padded) bin totals ----
__global__ __launch_bounds__(1024) void scan_bins(
    const int* __restrict__ bintotal, int* __restrict__ binbase, int NBIN)
{
    __shared__ int s[1024];
    int t = threadIdx.x;
    int i0 = 2 * t, i1 = 2 * t + 1;
    int p0 = (i0 < NBIN) ? ((bintotal[i0] + 1) & ~1) : 0;
    int p1 = (i1 < NBIN) ? ((bintotal[i1] + 1) & ~1) : 0;
    int v = p0 + p1;
    s[t] = v;
    __syncthreads();
    for (int o = 1; o < 1024; o <<= 1) {
        int u = (t >= o) ? s[t - o] : 0;
        __syncthreads();
        s[t] += u;
        __syncthreads();
    }
    int excl = s[t] - v;
    if (i0 < NBIN) binbase[i0] = excl;
    if (i1 < NBIN) binbase[i1] = excl + p0;
}

// ---- D. partition: 512 thr, int4 loads, 48KB LDS, binary-search flush ----
__global__ __launch_bounds__(512) void partition_kernel(
    const int* __restrict__ ei, const float* __restrict__ ea,
    const int* __restrict__ ofsT, const int* __restrict__ binbase,
    u64* __restrict__ pay, int E, int NBIN, int nPB)
{
    __shared__ unsigned short lofsw[NBINMAX + 1];
    __shared__ int lcur[NBINMAX];
    __shared__ int lbase[NBINMAX];
    __shared__ u64 stag[2 * EPB];                  // 32 KB
    int blk = blockIdx.x, tid = threadIdx.x;
    int e0 = blk * EPB;

    for (int i = tid; i < NBIN; i += 512) lcur[i] = 0;
    __syncthreads();

    int4 rr, cc; float4 av; bool full = (e0 + EPB <= E);
    if (full) {
        rr = *(const int4*)(ei + e0 + tid * 4);
        cc = *(const int4*)(ei + E + e0 + tid * 4);
        av = *(const float4*)(ea + e0 + tid * 4);
        atomicAdd(&lcur[(2 * cc.x) >> 7], 1); atomicAdd(&lcur[(2 * rr.x + 1) >> 7], 1);
        atomicAdd(&lcur[(2 * cc.y) >> 7], 1); atomicAdd(&lcur[(2 * rr.y + 1) >> 7], 1);
        atomicAdd(&lcur[(2 * cc.z) >> 7], 1); atomicAdd(&lcur[(2 * rr.z + 1) >> 7], 1);
        atomicAdd(&lcur[(2 * cc.w) >> 7], 1); atomicAdd(&lcur[(2 * rr.w + 1) >> 7], 1);
    } else {
        int rs[4], cs[4]; float as[4];
        #pragma unroll
        for (int j = 0; j < 4; ++j) {
            int e = e0 + tid * 4 + j;
            if (e < E) {
                rs[j] = ei[e]; cs[j] = ei[E + e]; as[j] = ea[e];
                atomicAdd(&lcur[(2 * cs[j]) >> 7], 1);
                atomicAdd(&lcur[(2 * rs[j] + 1) >> 7], 1);
            } else { rs[j] = 0; cs[j] = 0; as[j] = 0.0f; }
        }
        rr = make_int4(rs[0], rs[1], rs[2], rs[3]);
        cc = make_int4(cs[0], cs[1], cs[2], cs[3]);
        av = make_float4(as[0], as[1], as[2], as[3]);
    }
    __syncthreads();

    if (tid < 64) {
        int runc = 0;
        for (int b0 = 0; b0 < NBIN; b0 += 64) {
            int i = b0 + tid;
            int v = (i < NBIN) ? lcur[i] : 0;
            int s = v;
            #pragma unroll
            for (int d = 1; d < 64; d <<= 1) {
                int t2 = __shfl_up(s, d, 64);
                if (tid >= d) s += t2;
            }
            if (i < NBIN) lofsw[i] = (unsigned short)(s - v + runc);
            runc += __shfl(s, 63, 64);
        }
        if (tid == 0) lofsw[NBIN] = (unsigned short)runc;
    }
    __syncthreads();

    for (int i = tid; i < NBIN; i += 512) {
        lcur[i] = 0;
        lbase[i] = binbase[i] + ofsT[(long long)i * nPB + blk];
    }
    __syncthreads();

    {
        int rs[4] = {rr.x, rr.y, rr.z, rr.w};
        int cs[4] = {cc.x, cc.y, cc.z, cc.w};
        float as[4] = {av.x, av.y, av.z, av.w};
        #pragma unroll
        for (int j = 0; j < 4; ++j) {
            int e = e0 + tid * 4 + j;
            if (e < E) {
                unsigned int ab = (unsigned int)__float_as_int(as[j]);
                {
                    int key = 2 * cs[j]; int bin = key >> 7;      // mi: src = r
                    int t2 = atomicAdd(&lcur[bin], 1);
                    stag[(int)lofsw[bin] + t2] = ((u64)ab << 32) |
                        (unsigned int)(rs[j] | ((key & 127) << 17));
                }
                {
                    int key = 2 * rs[j] + 1; int bin = key >> 7;  // mo: src = c
                    int t2 = atomicAdd(&lcur[bin], 1);
                    stag[(int)lofsw[bin] + t2] = ((u64)ab << 32) |
                        (unsigned int)(cs[j] | ((key & 127) << 17));
                }
            }
        }
    }
    __syncthreads();

    int total = lofsw[NBIN];
    for (int i = tid; i < total; i += 512) {
        int lo = 0, hi = NBIN;
        while (hi - lo > 1) {
            int mid = (lo + hi) >> 1;
            if ((int)lofsw[mid] <= i) lo = mid; else hi = mid;
        }
        pay[lbase[lo] + (i - (int)lofsw[lo])] = stag[i];
    }
}

// ---- E. accum: 512 thr / 8 waves; quad chains (R15 proven form) ----
__global__ __launch_bounds__(512) void accum_sortgather(
    const float* __restrict__ x,
    const int* __restrict__ binbase, const int* __restrict__ bintotal,
    const u64* __restrict__ pay,
    float* __restrict__ mi, float* __restrict__ mo, int NK)
{
    __shared__ u64 srec[CAP];
    __shared__ int lcnt[KEYS_PER_BIN];
    __shared__ int lofs[KEYS_PER_BIN];
    __shared__ int lcur[KEYS_PER_BIN];

    int b = blockIdx.x, tid = threadIdx.x;
    int base = binbase[b];
    int n    = bintotal[b];
    int wid  = tid >> 6;
    int lane = tid & 63;
    int half = lane >> 5;
    int feat = lane & 31;

    float accA[4], accB[4], accC[4], accD[4];
    #pragma unroll
    for (int p = 0; p < 4; ++p) {
        accA[p] = 0.0f; accB[p] = 0.0f; accC[p] = 0.0f; accD[p] = 0.0f;
    }

    for (int c0 = 0; c0 < n; c0 += CAP) {
        int cn = min(n - c0, CAP);
        if (tid < KEYS_PER_BIN) lcnt[tid] = 0;
        __syncthreads();
        for (int i = tid; i < cn; i += 512)
            atomicAdd(&lcnt[((int)pay[base + c0 + i] >> 17) & 127], 1);
        __syncthreads();
        if (tid < 64) {
            int v0 = lcnt[2 * tid], v1 = lcnt[2 * tid + 1];
            int s = v0 + v1, ss = s;
            #pragma unroll
            for (int d = 1; d < 64; d <<= 1) {
                int t = __shfl_up(ss, d, 64);
                if (tid >= d) ss += t;
            }
            int excl = ss - s;
            lofs[2 * tid] = excl;      lofs[2 * tid + 1] = excl + v0;
            lcur[2 * tid] = excl;      lcur[2 * tid + 1] = excl + v0;
        }
        __syncthreads();
        for (int i = tid; i < cn; i += 512) {
            u64 v = pay[base + c0 + i];
            int t2 = atomicAdd(&lcur[((int)v >> 17) & 127], 1);
            srec[t2] = v;
        }
        __syncthreads();

        #pragma unroll
        for (int p = 0; p < 4; ++p) {
            int kb = wid * 16 + 4 * p;
            int s0 = lofs[kb + 0], e0 = s0 + lcnt[kb + 0];
            int s1 = lofs[kb + 1], e1 = s1 + lcnt[kb + 1];
            int s2 = lofs[kb + 2], e2 = s2 + lcnt[kb + 2];
            int s3 = lofs[kb + 3], e3 = s3 + lcnt[kb + 3];
            int i0 = s0 + half, i1 = s1 + half, i2 = s2 + half, i3 = s3 + half;
            float a0 = accA[p], a1 = accB[p], a2 = accC[p], a3 = accD[p];
            while (i0 < e0 && i1 < e1 && i2 < e2 && i3 < e3) {
                u64 r0 = srec[i0], r1 = srec[i1], r2 = srec[i2], r3 = srec[i3];
                float x0 = x[(long long)((int)r0 & 0x1FFFF) * DFEAT + feat];
                float x1 = x[(long long)((int)r1 & 0x1FFFF) * DFEAT + feat];
                float x2 = x[(long long)((int)r2 & 0x1FFFF) * DFEAT + feat];
                float x3 = x[(long long)((int)r3 & 0x1FFFF) * DFEAT + feat];
                a0 = fmaf(__int_as_float((int)(r0 >> 32)), x0, a0);
                a1 = fmaf(__int_as_float((int)(r1 >> 32)), x1, a1);
                a2 = fmaf(__int_as_float((int)(r2 >> 32)), x2, a2);
                a3 = fmaf(__int_as_float((int)(r3 >> 32)), x3, a3);
                i0 += 2; i1 += 2; i2 += 2; i3 += 2;
            }
            while (i0 < e0) {
                u64 rr = srec[i0];
                a0 = fmaf(__int_as_float((int)(rr >> 32)),
                          x[(long long)((int)rr & 0x1FFFF) * DFEAT + feat], a0);
                i0 += 2;
            }
            while (i1 < e1) {
                u64 rr = srec[i1];
                a1 = fmaf(__int_as_float((int)(rr >> 32)),
                          x[(long long)((int)rr & 0x1FFFF) * DFEAT + feat], a1);
                i1 += 2;
            }
            while (i2 < e2) {
                u64 rr = srec[i2];
                a2 = fmaf(__int_as_float((int)(rr >> 32)),
                          x[(long long)((int)rr & 0x1FFFF) * DFEAT + feat], a2);
                i2 += 2;
            }
            while (i3 < e3) {
                u64 rr = srec[i3];
                a3 = fmaf(__int_as_float((int)(rr >> 32)),
                          x[(long long)((int)rr & 0x1FFFF) * DFEAT + feat], a3);
                i3 += 2;
            }
            accA[p] = a0; accB[p] = a1; accC[p] = a2; accD[p] = a3;
        }
        __syncthreads();
    }

    int key0 = b * KEYS_PER_BIN + wid * 16;
    #pragma unroll
    for (int p = 0; p < 4; ++p) {
        float t0 = accA[p] + __shfl_xor(accA[p], 32, 64);
        float t1 = accB[p] + __shfl_xor(accB[p], 32, 64);
        float t2 = accC[p] + __shfl_xor(accC[p], 32, 64);
        float t3 = accD[p] + __shfl_xor(accD[p], 32, 64);
        float vA = half ? t2 : t0;
        float vB = half ? t3 : t1;
        int gkA = key0 + 4 * p + (half ? 2 : 0);
        int gkB = gkA + 1;
        if (gkA < NK) {
            int node = gkA >> 1;
            ((gkA & 1) ? mo : mi)[(long long)node * DFEAT + feat] = vA;
        }
        if (gkB < NK) {
            int node = gkB >> 1;
            ((gkB & 1) ? mo : mi)[(long long)node * DFEAT + feat] = vB;
        }
    }
}

// ---- F1. MLP layer 1 (R18 form): W1 in VGPR, 64-thr uniform-node blocks ----
__global__ __launch_bounds__(64, 4) void mlp_l1(
    const float* __restrict__ mi, const float* __restrict__ mo,
    const float* __restrict__ x,
    const float* __restrict__ W1, const float* __restrict__ b1,
    float* __restrict__ hbuf, int N)
{
    int o = threadIdx.x;

    float w1r[96];
    #pragma unroll
    for (int k = 0; k < 96; ++k) w1r[k] = W1[k * 64 + o];
    float bias1 = b1[o];

    for (int node = blockIdx.x; node < N; node += gridDim.x) {
        const float* Mi = mi + (long long)node * DFEAT;
        const float* Mo = mo + (long long)node * DFEAT;
        const float* Xr = x  + (long long)node * DFEAT;

        float a0 = bias1, a1 = 0.0f, a2 = 0.0f, a3 = 0.0f;
        #pragma unroll
        for (int k = 0; k < 32; k += 4) {
            a0 = fmaf(Mi[k + 0], w1r[k + 0], a0);
            a1 = fmaf(Mi[k + 1], w1r[k + 1], a1);
            a2 = fmaf(Mi[k + 2], w1r[k + 2], a2);
            a3 = fmaf(Mi[k + 3], w1r[k + 3], a3);
        }
        #pragma unroll
        for (int k = 0; k < 32; k += 4) {
            a0 = fmaf(Mo[k + 0], w1r[32 + k + 0], a0);
            a1 = fmaf(Mo[k + 1], w1r[32 + k + 1], a1);
            a2 = fmaf(Mo[k + 2], w1r[32 + k + 2], a2);
            a3 = fmaf(Mo[k + 3], w1r[32 + k + 3], a3);
        }
        #pragma unroll
        for (int k = 0; k < 32; k += 4) {
            a0 = fmaf(Xr[k + 0], w1r[64 + k + 0], a0);
            a1 = fmaf(Xr[k + 1], w1r[64 + k + 1], a1);
            a2 = fmaf(Xr[k + 2], w1r[64 + k + 2], a2);
            a3 = fmaf(Xr[k + 3], w1r[64 + k + 3], a3);
        }
        hbuf[(long long)node * OFEAT + o] = tanhf(((a0 + a1) + (a2 + a3)));
    }
}

// ---- F2. MLP layer 2 (R18 form) ----
__global__ __launch_bounds__(64, 5) void mlp_l2(
    const float* __restrict__ hbuf,
    const float* __restrict__ W2, const float* __restrict__ b2,
    float* __restrict__ out, int N)
{
    int o = threadIdx.x;

    float w2r[64];
    #pragma unroll
    for (int k = 0; k < 64; ++k) w2r[k] = W2[k * 64 + o];
    float bias2 = b2[o];

    for (int node = blockIdx.x; node < N; node += gridDim.x) {
        const float* H = hbuf + (long long)node * OFEAT;

        float c0 = bias2, c1 = 0.0f, c2 = 0.0f, c3 = 0.0f;
        #pragma unroll
        for (int k = 0; k < 64; k += 4) {
            c0 = fmaf(H[k + 0], w2r[k + 0], c0);
            c1 = fmaf(H[k + 1], w2r[k + 1], c1);
            c2 = fmaf(H[k + 2], w2r[k + 2], c2);
            c3 = fmaf(H[k + 3], w2r[k + 3], c3);
        }
        out[(long long)node * OFEAT + o] = tanhf(((c0 + c1) + (c2 + c3)));
    }
}

// ---- fallback: direct atomic scatter (ws too small / N too big) ----
__global__ __launch_bounds__(256) void edge_scatter_kernel(
    const float* __restrict__ x, const int* __restrict__ ei,
    const float* __restrict__ ea,
    float* __restrict__ mi, float* __restrict__ mo, int E)
{
    long long tid = (long long)blockIdx.x * blockDim.x + threadIdx.x;
    long long total = (long long)E * 8;
    if (tid >= total) return;
    int e = (int)(tid >> 3);
    int q = (int)(tid & 7);
    int r = ei[e];
    int c = ei[E + e];
    float a = ea[e];
    const float4* x4 = (const float4*)x;
    float4 xr = x4[(long long)r * 8 + q];
    float4 xc = x4[(long long)c * 8 + q];
    float* mip = mi + (long long)c * DFEAT + q * 4;
    float* mop = mo + (long long)r * DFEAT + q * 4;
    atomicAdd(mip + 0, a * xr.x); atomicAdd(mip + 1, a * xr.y);
    atomicAdd(mip + 2, a * xr.z); atomicAdd(mip + 3, a * xr.w);
    atomicAdd(mop + 0, a * xc.x); atomicAdd(mop + 1, a * xc.y);
    atomicAdd(mop + 2, a * xc.z); atomicAdd(mop + 3, a * xc.w);
}

// ---- fallback MLP (R15 readlane form) ----
__global__ __launch_bounds__(256) void mlp_reg_kernel(
    const float* __restrict__ mi, const float* __restrict__ mo,
    const float* __restrict__ x,
    const float* __restrict__ W1, const float* __restrict__ b1,
    const float* __restrict__ W2, const float* __restrict__ b2,
    float* __restrict__ out, int N)
{
    int o   = threadIdx.x & 63;
    int wid = threadIdx.x >> 6;

    float w1r[96], w2r[64];
    #pragma unroll
    for (int k = 0; k < 96; ++k) w1r[k] = W1[k * 64 + o];
    #pragma unroll
    for (int k = 0; k < 64; ++k) w2r[k] = W2[k * 64 + o];
    float bias1 = b1[o];
    float bias2 = b2[o];

    int stride = gridDim.x * 4;
    for (int node = blockIdx.x * 4 + wid; node < N; node += stride) {
        long long nb = (long long)node * DFEAT;
        float m01 = (o < 32) ? mi[nb + o] : mo[nb + (o - 32)];
        float m2v = (o < 32) ? x[nb + o] : 0.0f;

        float a0 = bias1, a1 = 0.0f, a2 = 0.0f, a3 = 0.0f;
        #pragma unroll
        for (int k = 0; k < 64; k += 4) {
            a0 = fmaf(rdlane(m01, k + 0), w1r[k + 0], a0);
            a1 = fmaf(rdlane(m01, k + 1), w1r[k + 1], a1);
            a2 = fmaf(rdlane(m01, k + 2), w1r[k + 2], a2);
            a3 = fmaf(rdlane(m01, k + 3), w1r[k + 3], a3);
        }
        #pragma unroll
        for (int k = 0; k < 32; k += 4) {
            a0 = fmaf(rdlane(m2v, k + 0), w1r[64 + k + 0], a0);
            a1 = fmaf(rdlane(m2v, k + 1), w1r[64 + k + 1], a1);
            a2 = fmaf(rdlane(m2v, k + 2), w1r[64 + k + 2], a2);
            a3 = fmaf(rdlane(m2v, k + 3), w1r[64 + k + 3], a3);
        }
        float h = tanhf(((a0 + a1) + (a2 + a3)));

        float c0 = bias2, c1 = 0.0f, c2 = 0.0f, c3 = 0.0f;
        #pragma unroll
        for (int k = 0; k < 64; k += 4) {
            c0 = fmaf(rdlane(h, k + 0), w2r[k + 0], c0);
            c1 = fmaf(rdlane(h, k + 1), w2r[k + 1], c1);
            c2 = fmaf(rdlane(h, k + 2), w2r[k + 2], c2);
            c3 = fmaf(rdlane(h, k + 3), w2r[k + 3], c3);
        }
        out[(long long)node * OFEAT + o] = tanhf(((c0 + c1) + (c2 + c3)));
    }
}

extern "C" void kernel_launch(void* const* d_in, const int* in_sizes, int n_in,
                              void* d_out, int out_size, void* d_ws, size_t ws_size,
                              hipStream_t stream) {
    const float* x  = (const float*)d_in[0];
    const int*   ei = (const int*)  d_in[1];
    const float* ea = (const float*)d_in[2];
    const float* W1 = (const float*)d_in[3];
    const float* b1 = (const float*)d_in[4];
    const float* W2 = (const float*)d_in[5];
    const float* b2 = (const float*)d_in[6];
    float* out = (float*)d_out;

    int N    = in_sizes[0] / DFEAT;              // 100000
    int E    = in_sizes[2];                      // 1600000
    int NK   = 2 * N;
    int NBIN = (NK + KEYS_PER_BIN - 1) / KEYS_PER_BIN;   // 1563
    int nPB  = (E + EPB - 1) / EPB;                      // 782

    float* mi = (float*)d_ws;
    float* mo = mi + (size_t)N * DFEAT;

    size_t paySlots = (size_t)2 * E + NBIN;
    size_t need = (size_t)N * DFEAT * 2 * 4
                + paySlots * 8
                + (size_t)nPB * NBIN * 4 * 2
                + (size_t)NBIN * 4 * 2 + 64;

    bool h_fits = (size_t)N * OFEAT * 4 <= paySlots * 8;

    if (ws_size >= need && N <= (1 << 17) && NBIN <= NBINMAX && h_fits) {
        u64* pay       = (u64*)(mo + (size_t)N * DFEAT);
        int* blockhist = (int*)(pay + paySlots);
        int* ofsT      = blockhist + (size_t)nPB * NBIN;
        int* bintotal  = ofsT + (size_t)nPB * NBIN;
        int* binbase   = bintotal + NBIN;

        hist_part<<<nPB, 512, 0, stream>>>(ei, blockhist, E, NBIN);
        colscan<<<NBIN, 64, 0, stream>>>(blockhist, ofsT, bintotal, nPB, NBIN);
        scan_bins<<<1, 1024, 0, stream>>>(bintotal, binbase, NBIN);
        partition_kernel<<<nPB, 512, 0, stream>>>(ei, ea, ofsT, binbase,
                                                  pay, E, NBIN, nPB);
        accum_sortgather<<<NBIN, 512, 0, stream>>>(x, binbase, bintotal, pay,
                                                   mi, mo, NK);
        float* hbuf = (float*)pay;               // pay dead after accum
        mlp_l1<<<4096, 64, 0, stream>>>(mi, mo, x, W1, b1, hbuf, N);
        mlp_l2<<<6144, 64, 0, stream>>>(hbuf, W2, b2, out, N);
    } else {
        hipMemsetAsync(d_ws, 0, (size_t)N * DFEAT * 2 * sizeof(float), stream);
        long long total = (long long)E * 8;
        int nblocks = (int)((total + 255) / 256);
        edge_scatter_kernel<<<nblocks, 256, 0, stream>>>(x, ei, ea, mi, mo, E);
        mlp_reg_kernel<<<512, 256, 0, stream>>>(mi, mo, x, W1, b1, W2, b2, out, N);
    }
}